// Round 3
// baseline (1020.124 us; speedup 1.0000x reference)
//
#include <hip/hip_runtime.h>

#define NPTS   4096
#define NB     8
#define M1     1024     // ceil(0.25*4096)
#define M2     820      // ceil(0.2*4096)
#define NEXTRA 1638     // int(8*1024*0.2)
#define MQ     9830     // 8*1024 + 1638
#define KK     16

typedef unsigned int u32;
typedef unsigned long long u64;
typedef float f32x2 __attribute__((ext_vector_type(2)));

// DPP lexicographic combine on (khi_,klo_) u64 key. VALU pipe.
// ctrl: 0x121/0x122/0x124/0x128 = row_ror 1/2/4/8 (16-lane rows),
// 0x142 = row_bcast15, 0x143 = row_bcast31 -> lane 63 holds the result.
#define DPP_MAX(CTRL) do {                                                         \
    u32 olo_ = (u32)__builtin_amdgcn_update_dpp((int)klo_, (int)klo_, CTRL, 0xF, 0xF, false); \
    u32 ohi_ = (u32)__builtin_amdgcn_update_dpp((int)khi_, (int)khi_, CTRL, 0xF, 0xF, false); \
    u64 ok_ = ((u64)ohi_ << 32) | olo_;                                            \
    u64 ck_ = ((u64)khi_ << 32) | klo_;                                            \
    if (ok_ > ck_) { klo_ = olo_; khi_ = ohi_; }                                   \
} while (0)

#define DPP_MIN(CTRL) do {                                                         \
    u32 olo_ = (u32)__builtin_amdgcn_update_dpp((int)klo_, (int)klo_, CTRL, 0xF, 0xF, false); \
    u32 ohi_ = (u32)__builtin_amdgcn_update_dpp((int)khi_, (int)khi_, CTRL, 0xF, 0xF, false); \
    u64 ok_ = ((u64)ohi_ << 32) | olo_;                                            \
    u64 ck_ = ((u64)khi_ << 32) | klo_;                                            \
    if (ok_ < ck_) { klo_ = olo_; khi_ = ohi_; }                                   \
} while (0)

// ---------------- FPS: one block (256 thr = 4 waves) per cloud ----------------
// Bit-exact vs jax: d = ((dx*dx+dy*dy)+dz*dz) f32 no-contract; min(MD,d);
// argmax tie -> lowest index. Per-step chain: pk dist update -> (val,j) strict->
// tree -> u64 DPP wave argmax -> winner xyz selected from owner registers,
// written to slots pre-barrier -> lgkmcnt-only barrier -> b128 slot reads ->
// 4-way compare gives next (xl,yl,zl) directly (no dependent position read).
// picks accumulate in LDS, flushed once at the end (no vmcnt in the loop).
__global__ __launch_bounds__(256) void fps_kernel(const float* __restrict__ pos,
                                                  int* __restrict__ picks) {
#pragma clang fp contract(off)
    __shared__ float sx[NPTS], sy[NPTS], sz[NPTS];
    __shared__ int sp[M1];
    __shared__ u64 skey[2][4];                 // per-parity, per-wave (dist,~idx)
    __shared__ float sxw[2][4], syw[2][4], szw[2][4];
    const int b = blockIdx.x;
    const int t = threadIdx.x;
    const float* cp = pos + (size_t)b * NPTS * 3;
    for (int i = t; i < NPTS * 3; i += 256) {
        float v = cp[i];
        int p = i / 3, c = i - p * 3;
        if (c == 0) sx[p] = v;
        else if (c == 1) sy[p] = v;
        else sz[p] = v;
    }
    if (t == 0) sp[0] = 0;
    __syncthreads();

    f32x2 X[8], Y[8], Z[8], MD[8];
#pragma unroll
    for (int r = 0; r < 8; ++r) {
        int p0 = (2 * r) * 256 + t, p1 = p0 + 256;
        X[r] = f32x2{sx[p0], sx[p1]};
        Y[r] = f32x2{sy[p0], sy[p1]};
        Z[r] = f32x2{sz[p0], sz[p1]};
        MD[r] = f32x2{__builtin_inff(), __builtin_inff()};
    }
    float xl = sx[0], yl = sy[0], zl = sz[0];
    const int wave = t >> 6;

    for (int s = 1; s < M1; ++s) {
        const int par = s & 1;
        const f32x2 xl2 = f32x2{xl, xl};
        const f32x2 yl2 = f32x2{yl, yl};
        const f32x2 zl2 = f32x2{zl, zl};
        float mv[16];
        int mj[16];
#pragma unroll
        for (int r = 0; r < 8; ++r) {
            f32x2 dx = X[r] - xl2;
            f32x2 dy = Y[r] - yl2;
            f32x2 dz = Z[r] - zl2;
            f32x2 d = (dx * dx + dy * dy) + dz * dz;        // contract(off)
            f32x2 m = __builtin_elementwise_min(MD[r], d);  // v_pk_min_f32
            MD[r] = m;
            mv[2 * r] = m[0];     mj[2 * r] = 2 * r;
            mv[2 * r + 1] = m[1]; mj[2 * r + 1] = 2 * r + 1;
        }
        // (val, j) max tree; left slot always has lower point index, so strict >
        // keeps the lowest index on ties (matches jnp.argmax).
#pragma unroll
        for (int st = 8; st >= 1; st >>= 1) {
#pragma unroll
            for (int i = 0; i < 16; ++i) {
                if (i < st) {
                    if (mv[i + st] > mv[i]) { mv[i] = mv[i + st]; mj[i] = mj[i + st]; }
                }
            }
        }
        // lane key: dist bits (>=0, so bit order = value order) | ~idx
        u32 klo_ = ~(u32)((mj[0] << 8) + t);
        u32 khi_ = __float_as_uint(mv[0]);
        DPP_MAX(0x121); DPP_MAX(0x122); DPP_MAX(0x124); DPP_MAX(0x128);
        DPP_MAX(0x142); DPP_MAX(0x143);
        // lane 63 has the wave winner: publish key
        if ((t & 63) == 63) skey[par][wave] = ((u64)khi_ << 32) | klo_;
        const int idx = (int)~(u32)__builtin_amdgcn_readlane((int)klo_, 63); // uniform
        // winner's xyz from the owner lane's registers (uniform branch on j)
        const int j = idx >> 8;
        f32x2 xp, yp, zp;
        switch (j >> 1) {
            case 0: xp = X[0]; yp = Y[0]; zp = Z[0]; break;
            case 1: xp = X[1]; yp = Y[1]; zp = Z[1]; break;
            case 2: xp = X[2]; yp = Y[2]; zp = Z[2]; break;
            case 3: xp = X[3]; yp = Y[3]; zp = Z[3]; break;
            case 4: xp = X[4]; yp = Y[4]; zp = Z[4]; break;
            case 5: xp = X[5]; yp = Y[5]; zp = Z[5]; break;
            case 6: xp = X[6]; yp = Y[6]; zp = Z[6]; break;
            default: xp = X[7]; yp = Y[7]; zp = Z[7]; break;
        }
        const int h = j & 1;
        if ((idx & 255) == t) {                 // exactly one lane in this wave
            sxw[par][wave] = h ? xp[1] : xp[0];
            syw[par][wave] = h ? yp[1] : yp[0];
            szw[par][wave] = h ? zp[1] : zp[0];
        }
        // LDS-only drain + barrier (no vmcnt: nothing global in the loop)
        asm volatile("s_waitcnt lgkmcnt(0)\n\ts_barrier" ::: "memory");
        // SoA slots -> vector reads
        u64 k0 = skey[par][0], k1 = skey[par][1], k2 = skey[par][2], k3 = skey[par][3];
        float x0 = sxw[par][0], x1 = sxw[par][1], x2 = sxw[par][2], x3 = sxw[par][3];
        float y0 = syw[par][0], y1 = syw[par][1], y2 = syw[par][2], y3 = syw[par][3];
        float z0 = szw[par][0], z1 = szw[par][1], z2 = szw[par][2], z3 = szw[par][3];
        u64 bk = k0; xl = x0; yl = y0; zl = z0;
        if (k1 > bk) { bk = k1; xl = x1; yl = y1; zl = z1; }
        if (k2 > bk) { bk = k2; xl = x2; yl = y2; zl = z2; }
        if (k3 > bk) { bk = k3; xl = x3; yl = y3; zl = z3; }
        if (t == 0) sp[s] = (int)~(u32)bk;
    }
    __syncthreads();
    for (int i = t; i < M1; i += 256) picks[b * M1 + i] = sp[i];
}

// ---------------- build combined_idx + row ----------------
__global__ __launch_bounds__(256) void build_kernel(const int* __restrict__ picks,
                                                    int* __restrict__ out) {
    int i = blockIdx.x * 256 + threadIdx.x;
    if (i < MQ) {
        int v;
        if (i < NB * M1) {
            int b = i >> 10;
            v = b * NPTS + picks[i];
        } else {
            int e = i - NB * M1;
            int b = e / M2;
            int j = e - b * M2;
            v = b * NPTS + picks[b * M1 + j];      // extra = prefix of base FPS
        }
        out[i] = v;
    }
    if (i < MQ * KK) {
        out[MQ + i] = i >> 4;                      // row = repeat(arange(MQ), 16)
    }
}

// ---------------- kNN: one wave per query ----------------
__global__ __launch_bounds__(256) void knn_kernel(const float* __restrict__ pos,
                                                  int* __restrict__ out) {
#pragma clang fp contract(off)
    const int q = blockIdx.x * 4 + (threadIdx.x >> 6);
    const int l = threadIdx.x & 63;
    if (q >= MQ) return;
    const int cidx = out[q];                 // combined_idx[q] (from build_kernel)
    const int qb = cidx >> 12;
    const float qx = pos[(size_t)cidx * 3 + 0];
    const float qy = pos[(size_t)cidx * 3 + 1];
    const float qz = pos[(size_t)cidx * 3 + 2];
    const float* cp = pos + (size_t)qb * NPTS * 3;
    float D[64];
    float lv = __builtin_inff(); int li = 0;
#pragma unroll
    for (int j = 0; j < 64; ++j) {
        int p = j * 64 + l;
        float dx = cp[p * 3 + 0] - qx;
        float dy = cp[p * 3 + 1] - qy;
        float dz = cp[p * 3 + 2] - qz;
        float d = dx * dx + dy * dy + dz * dz;   // contract(off)
        D[j] = d;
        if (d < lv) { lv = d; li = p; }          // strict < keeps lowest index
    }
    unsigned long long mask = 0;
    int* colout = out + MQ + MQ * KK + q * KK;
    for (int r = 0; r < KK; ++r) {
        u32 klo_ = (u32)li, khi_ = __float_as_uint(lv);
        DPP_MIN(0x121); DPP_MIN(0x122); DPP_MIN(0x124); DPP_MIN(0x128);
        DPP_MIN(0x142); DPP_MIN(0x143);
        u32 bi = (u32)__builtin_amdgcn_readlane((int)klo_, 63);
        if (l == 0) colout[r] = qb * NPTS + (int)bi;
        if ((bi & 63) == (u32)l) mask |= 1ull << (bi >> 6);  // owner masks its slot
        lv = __builtin_inff(); li = 0;
#pragma unroll
        for (int j = 0; j < 64; ++j) {
            bool act = ((mask >> j) & 1ull) == 0ull;
            float d = D[j];
            if (act && d < lv) { lv = d; li = j * 64 + l; }
        }
    }
}

extern "C" void kernel_launch(void* const* d_in, const int* in_sizes, int n_in,
                              void* d_out, int out_size, void* d_ws, size_t ws_size,
                              hipStream_t stream) {
    const float* pos = (const float*)d_in[0];
    int* picks = (int*)d_ws;                 // 8*1024 int32
    int* out = (int*)d_out;
    fps_kernel<<<NB, 256, 0, stream>>>(pos, picks);
    build_kernel<<<(MQ * KK + 255) / 256, 256, 0, stream>>>(picks, out);
    knn_kernel<<<(MQ + 3) / 4, 256, 0, stream>>>(pos, out);
}

// Round 4
// 848.288 us; speedup vs baseline: 1.2026x; 1.2026x over previous
//
#include <hip/hip_runtime.h>

#define NPTS   4096
#define NB     8
#define M1     1024     // ceil(0.25*4096)
#define M2     820      // ceil(0.2*4096)
#define NEXTRA 1638     // int(8*1024*0.2)
#define MQ     9830     // 8*1024 + 1638
#define KK     16

typedef unsigned int u32;
typedef unsigned long long u64;
typedef float f32x2 __attribute__((ext_vector_type(2)));

// DPP lexicographic combine on (khi_,klo_) u64 key. VALU pipe.
// ctrl: 0x121/0x122/0x124/0x128 = row_ror 1/2/4/8 (16-lane rows),
// 0x142 = row_bcast15, 0x143 = row_bcast31 -> lane 63 holds the result.
// (Chain proven bit-exact in R2/R3 across all 8x1023 picks.)
#define DPP_MAX(CTRL) do {                                                         \
    u32 olo_ = (u32)__builtin_amdgcn_update_dpp((int)klo_, (int)klo_, CTRL, 0xF, 0xF, false); \
    u32 ohi_ = (u32)__builtin_amdgcn_update_dpp((int)khi_, (int)khi_, CTRL, 0xF, 0xF, false); \
    u64 ok_ = ((u64)ohi_ << 32) | olo_;                                            \
    u64 ck_ = ((u64)khi_ << 32) | klo_;                                            \
    if (ok_ > ck_) { klo_ = olo_; khi_ = ohi_; }                                   \
} while (0)

#define DPP_MIN(CTRL) do {                                                         \
    u32 olo_ = (u32)__builtin_amdgcn_update_dpp((int)klo_, (int)klo_, CTRL, 0xF, 0xF, false); \
    u32 ohi_ = (u32)__builtin_amdgcn_update_dpp((int)khi_, (int)khi_, CTRL, 0xF, 0xF, false); \
    u64 ok_ = ((u64)ohi_ << 32) | olo_;                                            \
    u64 ck_ = ((u64)khi_ << 32) | klo_;                                            \
    if (ok_ < ck_) { klo_ = olo_; khi_ = ohi_; }                                   \
} while (0)

// ---------------- FPS: one block (256 thr = 4 waves) per cloud ----------------
// Bit-exact vs jax: d = ((dx*dx+dy*dy)+dz*dz) f32 no-contract; min(MD,d);
// argmax tie -> lowest index (u64 key = dist_bits<<32 | ~idx, max-reduced).
// Per-step chain: pk dist update -> (val,idx) strict-> tree -> [issue scattered
// LDS read of own candidate xyz; latency hidden under DPP] -> u64 DPP wave
// argmax -> readlane winner key -> winner lane (1 v_cmp, branchless exec mask)
// publishes {key,x,y,z} to its wave slot -> lgkmcnt-only barrier -> 4-slot
// select gives (xl,yl,zl) AND winner idx directly. No dependent position read,
// no switch, no vmcnt in the loop path (t0's global picks store never waited).
__global__ __launch_bounds__(256) void fps_kernel(const float* __restrict__ pos,
                                                  int* __restrict__ picks) {
#pragma clang fp contract(off)
    __shared__ float sx[NPTS], sy[NPTS], sz[NPTS];
    __shared__ float sslot[2][4][8];   // per parity, per wave: {klo,khi,x,y,z,pad..}
    const int b = blockIdx.x;
    const int t = threadIdx.x;
    const float* cp = pos + (size_t)b * NPTS * 3;
    for (int i = t; i < NPTS * 3; i += 256) {
        float v = cp[i];
        int p = i / 3, c = i - p * 3;
        if (c == 0) sx[p] = v;
        else if (c == 1) sy[p] = v;
        else sz[p] = v;
    }
    __syncthreads();

    f32x2 X[8], Y[8], Z[8], MD[8];
    int pidx[16];                       // candidate index constants, in regs
#pragma unroll
    for (int r = 0; r < 8; ++r) {
        int p0 = (2 * r) * 256 + t, p1 = p0 + 256;
        X[r] = f32x2{sx[p0], sx[p1]};
        Y[r] = f32x2{sy[p0], sy[p1]};
        Z[r] = f32x2{sz[p0], sz[p1]};
        MD[r] = f32x2{__builtin_inff(), __builtin_inff()};
        pidx[2 * r] = p0; pidx[2 * r + 1] = p1;
    }
    if (t == 0) picks[b * M1] = 0;
    float xl = sx[0], yl = sy[0], zl = sz[0];
    const int wave = t >> 6;

    for (int s = 1; s < M1; ++s) {
        const int par = s & 1;
        const f32x2 xl2 = f32x2{xl, xl};
        const f32x2 yl2 = f32x2{yl, yl};
        const f32x2 zl2 = f32x2{zl, zl};
        float mv[16];
        int mi[16];
#pragma unroll
        for (int r = 0; r < 8; ++r) {
            f32x2 dx = X[r] - xl2;
            f32x2 dy = Y[r] - yl2;
            f32x2 dz = Z[r] - zl2;
            f32x2 d = (dx * dx + dy * dy) + dz * dz;        // contract(off)
            f32x2 m = __builtin_elementwise_min(MD[r], d);  // v_pk_min_f32
            MD[r] = m;
            mv[2 * r] = m[0];     mi[2 * r] = pidx[2 * r];
            mv[2 * r + 1] = m[1]; mi[2 * r + 1] = pidx[2 * r + 1];
        }
        // (val, idx) max tree; left slot always lower index -> strict > keeps
        // lowest index on ties (matches jnp.argmax).
#pragma unroll
        for (int st = 8; st >= 1; st >>= 1) {
#pragma unroll
            for (int i = 0; i < 16; ++i) {
                if (i < st) {
                    if (mv[i + st] > mv[i]) { mv[i] = mv[i + st]; mi[i] = mi[i + st]; }
                }
            }
        }
        const int ci = mi[0];
        // own-candidate xyz: scattered LDS reads (bank alias 2-way = free),
        // latency hidden under the DPP chain below
        const float cx = sx[ci], cy = sy[ci], cz = sz[ci];
        // lane key: dist bits (>=0, bit order = value order) | ~idx
        u32 klo_ = ~(u32)ci;
        u32 khi_ = __float_as_uint(mv[0]);
        const u32 mylo = klo_;
        DPP_MAX(0x121); DPP_MAX(0x122); DPP_MAX(0x124); DPP_MAX(0x128);
        DPP_MAX(0x142); DPP_MAX(0x143);
        const u32 wlo = (u32)__builtin_amdgcn_readlane((int)klo_, 63);
        const u32 whi = (u32)__builtin_amdgcn_readlane((int)khi_, 63);
        if (mylo == wlo) {              // ~idx unique per lane: exactly 1 winner
            float4 v;
            v.x = __uint_as_float(wlo); v.y = __uint_as_float(whi);
            v.z = cx; v.w = cy;
            *(float4*)&sslot[par][wave][0] = v;
            sslot[par][wave][4] = cz;
        }
        // LDS-only drain + barrier (no vmcnt: picks store never blocks)
        asm volatile("s_waitcnt lgkmcnt(0)\n\ts_barrier" ::: "memory");
        const float4 a0 = *(const float4*)&sslot[par][0][0]; const float z0 = sslot[par][0][4];
        const float4 a1 = *(const float4*)&sslot[par][1][0]; const float z1 = sslot[par][1][4];
        const float4 a2 = *(const float4*)&sslot[par][2][0]; const float z2 = sslot[par][2][4];
        const float4 a3 = *(const float4*)&sslot[par][3][0]; const float z3 = sslot[par][3][4];
        u64 k0 = ((u64)__float_as_uint(a0.y) << 32) | __float_as_uint(a0.x);
        u64 k1 = ((u64)__float_as_uint(a1.y) << 32) | __float_as_uint(a1.x);
        u64 k2 = ((u64)__float_as_uint(a2.y) << 32) | __float_as_uint(a2.x);
        u64 k3 = ((u64)__float_as_uint(a3.y) << 32) | __float_as_uint(a3.x);
        u64 bk = k0; xl = a0.z; yl = a0.w; zl = z0;
        if (k1 > bk) { bk = k1; xl = a1.z; yl = a1.w; zl = z1; }
        if (k2 > bk) { bk = k2; xl = a2.z; yl = a2.w; zl = z2; }
        if (k3 > bk) { bk = k3; xl = a3.z; yl = a3.w; zl = z3; }
        if (t == 0) picks[b * M1 + s] = (int)~(u32)bk;
    }
}

// ---------------- build combined_idx + row ----------------
__global__ __launch_bounds__(256) void build_kernel(const int* __restrict__ picks,
                                                    int* __restrict__ out) {
    int i = blockIdx.x * 256 + threadIdx.x;
    if (i < MQ) {
        int v;
        if (i < NB * M1) {
            int b = i >> 10;
            v = b * NPTS + picks[i];
        } else {
            int e = i - NB * M1;
            int b = e / M2;
            int j = e - b * M2;
            v = b * NPTS + picks[b * M1 + j];      // extra = prefix of base FPS
        }
        out[i] = v;
    }
    if (i < MQ * KK) {
        out[MQ + i] = i >> 4;                      // row = repeat(arange(MQ), 16)
    }
}

// ---------------- kNN: one wave per query ----------------
__global__ __launch_bounds__(256) void knn_kernel(const float* __restrict__ pos,
                                                  int* __restrict__ out) {
#pragma clang fp contract(off)
    const int q = blockIdx.x * 4 + (threadIdx.x >> 6);
    const int l = threadIdx.x & 63;
    if (q >= MQ) return;
    const int cidx = out[q];                 // combined_idx[q] (from build_kernel)
    const int qb = cidx >> 12;
    const float qx = pos[(size_t)cidx * 3 + 0];
    const float qy = pos[(size_t)cidx * 3 + 1];
    const float qz = pos[(size_t)cidx * 3 + 2];
    const float* cp = pos + (size_t)qb * NPTS * 3;
    float D[64];
    float lv = __builtin_inff(); int li = 0;
#pragma unroll
    for (int j = 0; j < 64; ++j) {
        int p = j * 64 + l;
        float dx = cp[p * 3 + 0] - qx;
        float dy = cp[p * 3 + 1] - qy;
        float dz = cp[p * 3 + 2] - qz;
        float d = dx * dx + dy * dy + dz * dz;   // contract(off)
        D[j] = d;
        if (d < lv) { lv = d; li = p; }          // strict < keeps lowest index
    }
    unsigned long long mask = 0;
    int* colout = out + MQ + MQ * KK + q * KK;
    for (int r = 0; r < KK; ++r) {
        u32 klo_ = (u32)li, khi_ = __float_as_uint(lv);
        DPP_MIN(0x121); DPP_MIN(0x122); DPP_MIN(0x124); DPP_MIN(0x128);
        DPP_MIN(0x142); DPP_MIN(0x143);
        u32 bi = (u32)__builtin_amdgcn_readlane((int)klo_, 63);
        if (l == 0) colout[r] = qb * NPTS + (int)bi;
        if ((bi & 63) == (u32)l) mask |= 1ull << (bi >> 6);  // owner masks its slot
        lv = __builtin_inff(); li = 0;
#pragma unroll
        for (int j = 0; j < 64; ++j) {
            bool act = ((mask >> j) & 1ull) == 0ull;
            float d = D[j];
            if (act && d < lv) { lv = d; li = j * 64 + l; }
        }
    }
}

extern "C" void kernel_launch(void* const* d_in, const int* in_sizes, int n_in,
                              void* d_out, int out_size, void* d_ws, size_t ws_size,
                              hipStream_t stream) {
    const float* pos = (const float*)d_in[0];
    int* picks = (int*)d_ws;                 // 8*1024 int32
    int* out = (int*)d_out;
    fps_kernel<<<NB, 256, 0, stream>>>(pos, picks);
    build_kernel<<<(MQ * KK + 255) / 256, 256, 0, stream>>>(picks, out);
    knn_kernel<<<(MQ + 3) / 4, 256, 0, stream>>>(pos, out);
}

// Round 5
// 798.590 us; speedup vs baseline: 1.2774x; 1.0622x over previous
//
#include <hip/hip_runtime.h>

#define NPTS   4096
#define NB     8
#define M1     1024     // ceil(0.25*4096)
#define M2     820      // ceil(0.2*4096)
#define NEXTRA 1638     // int(8*1024*0.2)
#define MQ     9830     // 8*1024 + 1638
#define KK     16

typedef unsigned int u32;
typedef unsigned long long u64;
typedef float f32x2 __attribute__((ext_vector_type(2)));

// DPP lexicographic combine on (khi_,klo_) u64 key. VALU pipe.
// ctrl: 0x121/0x122/0x124/0x128 = row_ror 1/2/4/8 (16-lane rows),
// 0x142 = row_bcast15, 0x143 = row_bcast31 -> lane 63 holds the result.
// (Proven bit-exact R2-R4 across all 8x1023 picks.)
#define DPP_MAX(CTRL) do {                                                         \
    u32 olo_ = (u32)__builtin_amdgcn_update_dpp((int)klo_, (int)klo_, CTRL, 0xF, 0xF, false); \
    u32 ohi_ = (u32)__builtin_amdgcn_update_dpp((int)khi_, (int)khi_, CTRL, 0xF, 0xF, false); \
    u64 ok_ = ((u64)ohi_ << 32) | olo_;                                            \
    u64 ck_ = ((u64)khi_ << 32) | klo_;                                            \
    if (ok_ > ck_) { klo_ = olo_; khi_ = ohi_; }                                   \
} while (0)

#define DPP_MIN(CTRL) do {                                                         \
    u32 olo_ = (u32)__builtin_amdgcn_update_dpp((int)klo_, (int)klo_, CTRL, 0xF, 0xF, false); \
    u32 ohi_ = (u32)__builtin_amdgcn_update_dpp((int)khi_, (int)khi_, CTRL, 0xF, 0xF, false); \
    u64 ok_ = ((u64)ohi_ << 32) | olo_;                                            \
    u64 ck_ = ((u64)khi_ << 32) | klo_;                                            \
    if (ok_ < ck_) { klo_ = olo_; khi_ = ohi_; }                                   \
} while (0)

// ---------------- FPS: one block (256 thr = 4 waves) per cloud ----------------
// Bit-exact vs jax: d = ((dx*dx+dy*dy)+dz*dz) f32 no-contract; min(MD,d);
// argmax tie -> lowest index (u64 key = dist_bits<<32 | ~idx, max-reduced).
// Loop has ZERO global memory ops (picks in LDS, flushed at end) so
// __syncthreads()'s vmcnt(0) drain is free. Publish is branchless: every lane
// writes its {key,x,y,z} payload (winner -> wave slot, losers -> scratch via
// cndmask'd offset), so candidate-xyz loads can't sink into a branch and their
// latency hides under the DPP chain. Post-barrier 4-slot select gives next
// (xl,yl,zl) AND the pick index directly -- no dependent position read.
__global__ __launch_bounds__(256) void fps_kernel(const float* __restrict__ pos,
                                                  int* __restrict__ picks) {
#pragma clang fp contract(off)
    __shared__ float sx[NPTS], sy[NPTS], sz[NPTS];
    __shared__ int sp[M1];
    __shared__ float sbuf[64 + 256 * 8];   // [0..63]: 2par x 4wave x 8f slots; rest: scratch
    const int b = blockIdx.x;
    const int t = threadIdx.x;
    const float* cp = pos + (size_t)b * NPTS * 3;
    for (int i = t; i < NPTS * 3; i += 256) {
        float v = cp[i];
        int p = i / 3, c = i - p * 3;
        if (c == 0) sx[p] = v;
        else if (c == 1) sy[p] = v;
        else sz[p] = v;
    }
    if (t == 0) sp[0] = 0;
    __syncthreads();

    f32x2 X[8], Y[8], Z[8], MD[8];
#pragma unroll
    for (int r = 0; r < 8; ++r) {
        int p0 = (2 * r) * 256 + t, p1 = p0 + 256;
        X[r] = f32x2{sx[p0], sx[p1]};
        Y[r] = f32x2{sy[p0], sy[p1]};
        Z[r] = f32x2{sz[p0], sz[p1]};
        MD[r] = f32x2{__builtin_inff(), __builtin_inff()};
    }
    float xl = sx[0], yl = sy[0], zl = sz[0];
    const int wave = t >> 6;
    const int scrOff = 64 + t * 8;

    for (int s = 1; s < M1; ++s) {
        const int par = s & 1;
        const f32x2 xl2 = f32x2{xl, xl};
        const f32x2 yl2 = f32x2{yl, yl};
        const f32x2 zl2 = f32x2{zl, zl};
        float wv[8];
        int ws[8];                          // slot id 0..15 (inline consts)
#pragma unroll
        for (int r = 0; r < 8; ++r) {
            f32x2 dx = X[r] - xl2;
            f32x2 dy = Y[r] - yl2;
            f32x2 dz = Z[r] - zl2;
            f32x2 d = (dx * dx + dy * dy) + dz * dz;        // contract(off)
            f32x2 m = __builtin_elementwise_min(MD[r], d);
            MD[r] = m;
            // level 0: pair halves; slot 2r has lower point index -> strict >
            bool c = m[1] > m[0];
            wv[r] = c ? m[1] : m[0];
            ws[r] = c ? 2 * r + 1 : 2 * r;
        }
        // levels 1-3; left always lower slot -> strict > keeps lowest on ties
#pragma unroll
        for (int st = 4; st >= 1; st >>= 1) {
#pragma unroll
            for (int i = 0; i < 8; ++i) {
                if (i < st) {
                    if (wv[i + st] > wv[i]) { wv[i] = wv[i + st]; ws[i] = ws[i + st]; }
                }
            }
        }
        const int ci = (ws[0] << 8) + t;    // global candidate index
        // own-candidate xyz: consumed unconditionally below -> cannot sink;
        // latency hides under the DPP chain
        const float cx = sx[ci], cy = sy[ci], cz = sz[ci];
        u32 klo_ = ~(u32)ci;
        u32 khi_ = __float_as_uint(wv[0]);
        const u32 mylo = klo_, myhi = khi_;
        DPP_MAX(0x121); DPP_MAX(0x122); DPP_MAX(0x124); DPP_MAX(0x128);
        DPP_MAX(0x142); DPP_MAX(0x143);
        const u32 swlo = (u32)__builtin_amdgcn_readlane((int)klo_, 63);
        // branchless publish: winner -> wave slot, loser -> private scratch
        const int off = (mylo == swlo) ? ((par * 4 + wave) * 8) : scrOff;
        float4 pay;
        pay.x = __uint_as_float(mylo); pay.y = __uint_as_float(myhi);
        pay.z = cx; pay.w = cy;
        *(float4*)&sbuf[off] = pay;
        sbuf[off + 4] = cz;
        __syncthreads();                    // vmcnt already 0: lgkm-only in effect
        const int sb = par * 32;
        const float4 a0 = *(const float4*)&sbuf[sb + 0];  const float z0 = sbuf[sb + 4];
        const float4 a1 = *(const float4*)&sbuf[sb + 8];  const float z1 = sbuf[sb + 12];
        const float4 a2 = *(const float4*)&sbuf[sb + 16]; const float z2 = sbuf[sb + 20];
        const float4 a3 = *(const float4*)&sbuf[sb + 24]; const float z3 = sbuf[sb + 28];
        u64 k0 = ((u64)__float_as_uint(a0.y) << 32) | __float_as_uint(a0.x);
        u64 k1 = ((u64)__float_as_uint(a1.y) << 32) | __float_as_uint(a1.x);
        u64 k2 = ((u64)__float_as_uint(a2.y) << 32) | __float_as_uint(a2.x);
        u64 k3 = ((u64)__float_as_uint(a3.y) << 32) | __float_as_uint(a3.x);
        // 2-level select tree on (key, x, y, z)
        u64 ka = k0; float xa = a0.z, ya = a0.w, za = z0;
        if (k1 > ka) { ka = k1; xa = a1.z; ya = a1.w; za = z1; }
        u64 kb = k2; float xb = a2.z, yb = a2.w, zb = z2;
        if (k3 > kb) { kb = k3; xb = a3.z; yb = a3.w; zb = z3; }
        if (kb > ka) { ka = kb; xa = xb; ya = yb; za = zb; }
        xl = xa; yl = ya; zl = za;
        if (t == 0) sp[s] = (int)~(u32)ka;
    }
    __syncthreads();
    for (int i = t; i < M1; i += 256) picks[b * M1 + i] = sp[i];
}

// ---------------- build combined_idx + row ----------------
__global__ __launch_bounds__(256) void build_kernel(const int* __restrict__ picks,
                                                    int* __restrict__ out) {
    int i = blockIdx.x * 256 + threadIdx.x;
    if (i < MQ) {
        int v;
        if (i < NB * M1) {
            int b = i >> 10;
            v = b * NPTS + picks[i];
        } else {
            int e = i - NB * M1;
            int b = e / M2;
            int j = e - b * M2;
            v = b * NPTS + picks[b * M1 + j];      // extra = prefix of base FPS
        }
        out[i] = v;
    }
    if (i < MQ * KK) {
        out[MQ + i] = i >> 4;                      // row = repeat(arange(MQ), 16)
    }
}

// ---------------- kNN: one wave per query ----------------
__global__ __launch_bounds__(256) void knn_kernel(const float* __restrict__ pos,
                                                  int* __restrict__ out) {
#pragma clang fp contract(off)
    const int q = blockIdx.x * 4 + (threadIdx.x >> 6);
    const int l = threadIdx.x & 63;
    if (q >= MQ) return;
    const int cidx = out[q];                 // combined_idx[q] (from build_kernel)
    const int qb = cidx >> 12;
    const float qx = pos[(size_t)cidx * 3 + 0];
    const float qy = pos[(size_t)cidx * 3 + 1];
    const float qz = pos[(size_t)cidx * 3 + 2];
    const float* cp = pos + (size_t)qb * NPTS * 3;
    float D[64];
    float lv = __builtin_inff(); int li = 0;
#pragma unroll
    for (int j = 0; j < 64; ++j) {
        int p = j * 64 + l;
        float dx = cp[p * 3 + 0] - qx;
        float dy = cp[p * 3 + 1] - qy;
        float dz = cp[p * 3 + 2] - qz;
        float d = dx * dx + dy * dy + dz * dz;   // contract(off)
        D[j] = d;
        if (d < lv) { lv = d; li = p; }          // strict < keeps lowest index
    }
    unsigned long long mask = 0;
    int* colout = out + MQ + MQ * KK + q * KK;
    for (int r = 0; r < KK; ++r) {
        u32 klo_ = (u32)li, khi_ = __float_as_uint(lv);
        DPP_MIN(0x121); DPP_MIN(0x122); DPP_MIN(0x124); DPP_MIN(0x128);
        DPP_MIN(0x142); DPP_MIN(0x143);
        u32 bi = (u32)__builtin_amdgcn_readlane((int)klo_, 63);
        if (l == 0) colout[r] = qb * NPTS + (int)bi;
        if ((bi & 63) == (u32)l) mask |= 1ull << (bi >> 6);  // owner masks its slot
        lv = __builtin_inff(); li = 0;
#pragma unroll
        for (int j = 0; j < 64; ++j) {
            bool act = ((mask >> j) & 1ull) == 0ull;
            float d = D[j];
            if (act && d < lv) { lv = d; li = j * 64 + l; }
        }
    }
}

extern "C" void kernel_launch(void* const* d_in, const int* in_sizes, int n_in,
                              void* d_out, int out_size, void* d_ws, size_t ws_size,
                              hipStream_t stream) {
    const float* pos = (const float*)d_in[0];
    int* picks = (int*)d_ws;                 // 8*1024 int32
    int* out = (int*)d_out;
    fps_kernel<<<NB, 256, 0, stream>>>(pos, picks);
    build_kernel<<<(MQ * KK + 255) / 256, 256, 0, stream>>>(picks, out);
    knn_kernel<<<(MQ + 3) / 4, 256, 0, stream>>>(pos, out);
}